// Round 10
// baseline (236.790 us; speedup 1.0000x reference)
//
#include <hip/hip_runtime.h>

#define NH    16
#define DK    64
#define DIM   1024
#define BATCH 2
#define SEQ   2048
#define MROWS (BATCH*SEQ)   // 4096
#define QSCALE 0.18033688011112043f   // 0.125 * log2(e): folded into Q projection
#define SENT   -44.0f                 // sentinel in log2 domain; exp2(-44)=5.68e-14
#define PCONST 5.684341886080802e-14f // exp2(-44)

typedef unsigned short bfraw;
typedef __attribute__((ext_vector_type(8))) __bf16 bf16x8;
typedef __attribute__((ext_vector_type(4))) __bf16 bf16x4;
typedef __attribute__((ext_vector_type(8))) unsigned short u16x8;
typedef __attribute__((ext_vector_type(4))) unsigned short u16x4;
typedef __attribute__((ext_vector_type(4))) short s16x4;
typedef __attribute__((ext_vector_type(4))) float f32x4;

__device__ __forceinline__ float bf2f(bfraw u) {
    union { unsigned int i; float f; } x; x.i = ((unsigned int)u) << 16; return x.f;
}
__device__ __forceinline__ bfraw f2bf(float f) {          // RNE
    union { float f; unsigned int i; } x; x.f = f;
    unsigned int r = x.i + 0x7FFFu + ((x.i >> 16) & 1u);
    return (bfraw)(r >> 16);
}
__device__ __forceinline__ bfraw f2bf_trunc(float f) {    // truncate (bias ~2^-9 rel: fine at our margin)
    union { float f; unsigned int i; } x; x.f = f;
    return (bfraw)(x.i >> 16);
}
__device__ __forceinline__ u16x8 pack8_trunc(f32x4 a, f32x4 b) {
    u16x8 o;
    #pragma unroll
    for (int j = 0; j < 4; j++) { o[j] = f2bf_trunc(a[j]); o[4 + j] = f2bf_trunc(b[j]); }
    return o;
}
__device__ __forceinline__ float fexp2(float x) {
#if __has_builtin(__builtin_amdgcn_exp2f)
    return __builtin_amdgcn_exp2f(x);
#else
    return exp2f(x);
#endif
}

// K=16 bf16 MFMA, name hedged across ROCm spellings
__device__ __forceinline__ f32x4 mfma16(s16x4 a, s16x4 b, f32x4 c) {
#if __has_builtin(__builtin_amdgcn_mfma_f32_16x16x16_bf16)
    union { s16x4 s; bf16x4 h; } ua, ub; ua.s = a; ub.s = b;
    return __builtin_amdgcn_mfma_f32_16x16x16_bf16(ua.h, ub.h, c, 0, 0, 0);
#elif __has_builtin(__builtin_amdgcn_mfma_f32_16x16x16bf16_1k)
    return __builtin_amdgcn_mfma_f32_16x16x16bf16_1k(a, b, c, 0, 0, 0);
#else
    asm("v_mfma_f32_16x16x16_bf16 %0, %1, %2, %0" : "+v"(c) : "v"(a), "v"(b));
    return c;
#endif
}

__device__ __forceinline__ float block_reduce(float val, float* rbuf, int op) {
    const int lane = threadIdx.x & 63, wave = threadIdx.x >> 6;
    #pragma unroll
    for (int off = 32; off; off >>= 1) {
        float o = __shfl_xor(val, off, 64);
        val = op ? (val + o) : fmaxf(val, o);
    }
    if (lane == 0) rbuf[wave] = val;
    __syncthreads();
    float r = op ? (rbuf[0] + rbuf[1] + rbuf[2] + rbuf[3])
                 : fmaxf(fmaxf(rbuf[0], rbuf[1]), fmaxf(rbuf[2], rbuf[3]));
    __syncthreads();
    return r;
}

// ---------------- fp32 -> bf16 convert pass: WEIGHTS ONLY (X fused into qkv staging) ----------------
__global__ __launch_bounds__(256) void cvt_kernel(
        const float* __restrict__ w0, const float* __restrict__ w1, const float* __restrict__ w2,
        const float* __restrict__ w3, bfraw* __restrict__ Wb) {
    const int u = blockIdx.y;
    const float* src = (u == 0) ? w0 : (u == 1) ? w1 : (u == 2) ? w2 : w3;
    bfraw* dst = Wb + u * (DIM * DIM);
    int idx = (blockIdx.x * 256 + threadIdx.x) * 8;
    f32x4 a = *(const f32x4*)(src + idx);
    f32x4 b = *(const f32x4*)(src + idx + 4);
    u16x8 o;
    #pragma unroll
    for (int j = 0; j < 4; j++) { o[j] = f2bf(a[j]); o[4 + j] = f2bf(b[j]); }
    *(u16x8*)(dst + idx) = o;
}

// ---------------- 128x128 MFMA GEMM, BK=64, pipelined register staging ----------------
// AF32: A is fp32, converted to bf16 in-register during staging (trunc-pack).
__device__ __forceinline__ void gemm128_core(const void* __restrict__ Av, const bfraw* __restrict__ B,
                                             int m0, int n0, f32x4 acc[4][4], bool AF32_,
                                             const float* __restrict__ Af, const bfraw* __restrict__ Ab) {
    __shared__ __align__(16) bfraw As[128 * 64];
    __shared__ __align__(16) bfraw Bs[128 * 64];
    const int tid = threadIdx.x, wave = tid >> 6;
    const int lane = tid & 63, lrow = lane & 15, quad = lane >> 4;
    const int wy = wave >> 1, wx = wave & 1;
    const int swz = lrow & 7;
    const int srow = tid >> 2;
    const int cg0  = (tid & 3) << 1;
    const int gc   = cg0 << 3;
    const int e7   = srow & 7;
    const int o0 = ((cg0 ^ e7) << 3), o1 = (((cg0 | 1) ^ e7) << 3);
    (void)Av;

    u16x8 ha[4], hb[4];
    f32x4 fa[8];
    const float* qa0 = Af + (m0 + srow) * DIM + gc;
    const float* qa1 = Af + (m0 + 64 + srow) * DIM + gc;
    const bfraw* pa0 = Ab + (m0 + srow) * DIM + gc;
    const bfraw* pa1 = Ab + (m0 + 64 + srow) * DIM + gc;
    const bfraw* pb0 = B + (n0 + srow) * DIM + gc;
    const bfraw* pb1 = B + (n0 + 64 + srow) * DIM + gc;

    #pragma unroll
    for (int i = 0; i < 4; i++)
        #pragma unroll
        for (int j = 0; j < 4; j++) { f32x4 z = {0.f, 0.f, 0.f, 0.f}; acc[i][j] = z; }

    if (AF32_) {
        fa[0] = *(const f32x4*)(qa0);      fa[1] = *(const f32x4*)(qa0 + 4);
        fa[2] = *(const f32x4*)(qa0 + 8);  fa[3] = *(const f32x4*)(qa0 + 12);
        fa[4] = *(const f32x4*)(qa1);      fa[5] = *(const f32x4*)(qa1 + 4);
        fa[6] = *(const f32x4*)(qa1 + 8);  fa[7] = *(const f32x4*)(qa1 + 12);
    } else {
        ha[0] = *(const u16x8*)(pa0);      ha[1] = *(const u16x8*)(pa0 + 8);
        ha[2] = *(const u16x8*)(pa1);      ha[3] = *(const u16x8*)(pa1 + 8);
    }
    hb[0] = *(const u16x8*)(pb0);     hb[1] = *(const u16x8*)(pb0 + 8);
    hb[2] = *(const u16x8*)(pb1);     hb[3] = *(const u16x8*)(pb1 + 8);

    for (int k0 = 0; k0 < DIM; k0 += 64) {
        if (AF32_) {
            ha[0] = pack8_trunc(fa[0], fa[1]);  ha[1] = pack8_trunc(fa[2], fa[3]);
            ha[2] = pack8_trunc(fa[4], fa[5]);  ha[3] = pack8_trunc(fa[6], fa[7]);
        }
        __syncthreads();
        *(u16x8*)&As[srow * 64 + o0]        = ha[0];
        *(u16x8*)&As[srow * 64 + o1]        = ha[1];
        *(u16x8*)&As[(64 + srow) * 64 + o0] = ha[2];
        *(u16x8*)&As[(64 + srow) * 64 + o1] = ha[3];
        *(u16x8*)&Bs[srow * 64 + o0]        = hb[0];
        *(u16x8*)&Bs[srow * 64 + o1]        = hb[1];
        *(u16x8*)&Bs[(64 + srow) * 64 + o0] = hb[2];
        *(u16x8*)&Bs[(64 + srow) * 64 + o1] = hb[3];
        __syncthreads();
        if (k0 + 64 < DIM) {                        // prefetch k+1: overlaps MFMA below
            const int k1 = k0 + 64;
            if (AF32_) {
                fa[0] = *(const f32x4*)(qa0 + k1);      fa[1] = *(const f32x4*)(qa0 + k1 + 4);
                fa[2] = *(const f32x4*)(qa0 + k1 + 8);  fa[3] = *(const f32x4*)(qa0 + k1 + 12);
                fa[4] = *(const f32x4*)(qa1 + k1);      fa[5] = *(const f32x4*)(qa1 + k1 + 4);
                fa[6] = *(const f32x4*)(qa1 + k1 + 8);  fa[7] = *(const f32x4*)(qa1 + k1 + 12);
            } else {
                ha[0] = *(const u16x8*)(pa0 + k1);     ha[1] = *(const u16x8*)(pa0 + k1 + 8);
                ha[2] = *(const u16x8*)(pa1 + k1);     ha[3] = *(const u16x8*)(pa1 + k1 + 8);
            }
            hb[0] = *(const u16x8*)(pb0 + k1);     hb[1] = *(const u16x8*)(pb0 + k1 + 8);
            hb[2] = *(const u16x8*)(pb1 + k1);     hb[3] = *(const u16x8*)(pb1 + k1 + 8);
        }
        #pragma unroll
        for (int ks = 0; ks < 2; ks++) {
            const int c = (ks << 2) | quad;
            bf16x8 af[4], bfg[4];
            #pragma unroll
            for (int mi = 0; mi < 4; mi++)
                af[mi] = *(const bf16x8*)&As[(wy * 64 + mi * 16 + lrow) * 64 + ((c ^ swz) << 3)];
            #pragma unroll
            for (int ni = 0; ni < 4; ni++)
                bfg[ni] = *(const bf16x8*)&Bs[(wx * 64 + ni * 16 + lrow) * 64 + ((c ^ swz) << 3)];
            #pragma unroll
            for (int mi = 0; mi < 4; mi++)
                #pragma unroll
                for (int ni = 0; ni < 4; ni++)
                    acc[mi][ni] = __builtin_amdgcn_mfma_f32_16x16x32_bf16(af[mi], bfg[ni], acc[mi][ni], 0, 0, 0);
        }
    }
}

// ---------------- QKV projection: A = fp32 input, converted during staging ----------------
__global__ __launch_bounds__(256) void qkv_gemm(
        const float* __restrict__ Xq, const float* __restrict__ Xk, const float* __restrict__ Xv,
        const bfraw* __restrict__ Wb,
        bfraw* __restrict__ Qp, bfraw* __restrict__ Kp, bfraw* __restrict__ Vt) {
    const int which = blockIdx.z;
    const float* A = (which == 0) ? Xq : (which == 1) ? Xk : Xv;
    const bfraw* B = Wb + which * (DIM * DIM);
    bfraw* O = (which == 0) ? Qp : (which == 1) ? Kp : Vt;
    const int m0 = blockIdx.x * 128, n0 = blockIdx.y * 128;
    f32x4 acc[4][4];
    gemm128_core(nullptr, B, m0, n0, acc, true, A, nullptr);
    const int lane = threadIdx.x & 63, wave = threadIdx.x >> 6;
    const int lrow = lane & 15, quad = lane >> 4;
    const int wy = wave >> 1, wx = wave & 1;
    const float scale = (which == 0) ? QSCALE : 1.0f;
    #pragma unroll
    for (int mi = 0; mi < 4; mi++)
        #pragma unroll
        for (int ni = 0; ni < 4; ni++)
            #pragma unroll
            for (int i = 0; i < 4; i++) {
                int m = m0 + wy * 64 + mi * 16 + quad * 4 + i;
                int n = n0 + wx * 64 + ni * 16 + lrow;
                int b = m >> 11, s = m & (SEQ - 1), h = n >> 6, kk = n & (DK - 1);
                bfraw v = f2bf(acc[mi][ni][i] * scale);
                if (which == 2) O[(((b * NH + h) * DK) + kk) * SEQ + s] = v;
                else            O[(((b * NH + h) * SEQ) + s) * DK + kk] = v;
            }
}

// ---------------- V tile-boundary prefix sums ----------------
__global__ __launch_bounds__(256) void vsum_kernel(const bfraw* __restrict__ Vt,
                                                   float* __restrict__ Scum) {
    __shared__ float Ts[32][65];
    const int bh = blockIdx.x, tid = threadIdx.x;
    const int d = tid & 63, part = tid >> 6;
    const bfraw* vrow = Vt + (bh * DK + d) * SEQ;
    for (int qt = part * 8; qt < part * 8 + 8; qt++) {
        float s = 0.f;
        #pragma unroll
        for (int j = 0; j < 64; j += 8) {
            u16x8 v = *(const u16x8*)(vrow + qt * 64 + j);
            #pragma unroll
            for (int e = 0; e < 8; e++) s += bf2f(v[e]);
        }
        Ts[qt][d] = s;
    }
    __syncthreads();
    if (tid < 64) {
        float run = 0.f;
        for (int qt = 0; qt < 32; qt++) {
            Scum[(bh * 32 + qt) * 64 + tid] = run;
            run += Ts[qt][tid];
        }
    }
}

// ---------------- flash MFMA attention: transposed-S, in-register P, K/V dbuf ----------------
__global__ __launch_bounds__(256) void attn_flash(
        const bfraw* __restrict__ Qp, const bfraw* __restrict__ Kp, const bfraw* __restrict__ Vt,
        const float* __restrict__ Scum, const int* __restrict__ mask, bfraw* __restrict__ Ctx) {
    __shared__ __align__(16) bfraw Ks[2][64 * 64];
    __shared__ __align__(16) bfraw Vs[2][64 * 64];
    __shared__ unsigned short Mk[SEQ];
    const int bh = blockIdx.x, yy = blockIdx.y;
    const int gg = yy >> 3, jj = yy & 7;
    const int qt = (gg == 0) ? jj : (gg == 1) ? (31 - jj) : (gg == 2) ? (8 + jj) : (23 - jj);
    const int b = bh >> 4, h = bh & 15;
    const int tid = threadIdx.x, wave = tid >> 6, lane = tid & 63;
    const int lrow = lane & 15, quad = lane >> 4;
    const int baseK = ((b * NH + h) * SEQ) * DK;
    const int baseV = ((b * NH + h) * DK) * SEQ;
    const int qbase = qt * 64 + wave * 16;
    const int q_ln  = qbase + lrow;
    const int diagKt = qt * 64;
    const int ldr = tid >> 2;
    const int cg0 = (tid & 3) << 1;
    const int ldc = cg0 << 3;
    const int e7 = ldr & 7;
    const int cl0 = ((cg0 ^ e7) << 3), cl1 = (((cg0 | 1) ^ e7) << 3);

    for (int i = tid; i < SEQ; i += 256) Mk[i] = (unsigned short)(mask[b * SEQ + i] != 0);

    bf16x8 qf[2];
    qf[0] = *(const bf16x8*)(Qp + baseK + (qbase + lrow) * DK + quad * 8);
    qf[1] = *(const bf16x8*)(Qp + baseK + (qbase + lrow) * DK + 32 + quad * 8);

    f32x4 Oa[4];
    #pragma unroll
    for (int nd = 0; nd < 4; nd++) {
        f32x4 sv = *(const f32x4*)&Scum[(bh * 32 + qt) * 64 + nd * 16 + quad * 4];
        #pragma unroll
        for (int i = 0; i < 4; i++) Oa[nd][i] = PCONST * sv[i];
    }
    float lsum = 0.f;

    const int nt = (SEQ - diagKt) >> 6;
    int kt0 = diagKt;
    u16x8 k0 = *(const u16x8*)(Kp + baseK + (kt0 + ldr) * DK + ldc);
    u16x8 k1 = *(const u16x8*)(Kp + baseK + (kt0 + ldr) * DK + ldc + 8);
    u16x8 v0 = *(const u16x8*)(Vt + baseV + ldr * SEQ + kt0 + ldc);
    u16x8 v1 = *(const u16x8*)(Vt + baseV + ldr * SEQ + kt0 + ldc + 8);

    for (int t = 0; t < nt; t++, kt0 += 64) {
        bfraw* Kb = Ks[t & 1];
        bfraw* Vb = Vs[t & 1];
        *(u16x8*)&Kb[ldr * 64 + cl0] = k0;
        *(u16x8*)&Kb[ldr * 64 + cl1] = k1;
        *(u16x8*)&Vb[ldr * 64 + cl0] = v0;
        *(u16x8*)&Vb[ldr * 64 + cl1] = v1;
        if (t + 1 < nt) {
            const int kn = kt0 + 64;
            k0 = *(const u16x8*)(Kp + baseK + (kn + ldr) * DK + ldc);
            k1 = *(const u16x8*)(Kp + baseK + (kn + ldr) * DK + ldc + 8);
            v0 = *(const u16x8*)(Vt + baseV + ldr * SEQ + kn + ldc);
            v1 = *(const u16x8*)(Vt + baseV + ldr * SEQ + kn + ldc + 8);
        }
        __syncthreads();

        s16x4 pb[4];
        #pragma unroll
        for (int n = 0; n < 4; n++) {
            const int srow = n * 16 + lrow;
            bf16x8 kfa = *(const bf16x8*)&Kb[srow * 64 + ((quad ^ (lrow & 7)) << 3)];
            bf16x8 kfb = *(const bf16x8*)&Kb[srow * 64 + (((4 | quad) ^ (lrow & 7)) << 3)];
            f32x4 z = {0.f, 0.f, 0.f, 0.f};
            z = __builtin_amdgcn_mfma_f32_16x16x32_bf16(kfa, qf[0], z, 0, 0, 0);
            z = __builtin_amdgcn_mfma_f32_16x16x32_bf16(kfb, qf[1], z, 0, 0, 0);
            u16x4 pu;
            if (t == 0) {
                #pragma unroll
                for (int i = 0; i < 4; i++) {
                    int s = kt0 + n * 16 + quad * 4 + i;
                    bool valid = (Mk[s] != 0) && (s > q_ln);
                    float p = fexp2(valid ? z[i] : SENT);
                    lsum += p; pu[i] = f2bf_trunc(p);
                }
            } else {
                #pragma unroll
                for (int i = 0; i < 4; i++) {
                    int s = kt0 + n * 16 + quad * 4 + i;
                    float p = fexp2(Mk[s] ? z[i] : SENT);
                    lsum += p; pu[i] = f2bf_trunc(p);
                }
            }
            union { u16x4 u; s16x4 s; } cv; cv.u = pu; pb[n] = cv.s;
        }

        #pragma unroll
        for (int nd = 0; nd < 4; nd++) {
            const int d = nd * 16 + lrow;
            #pragma unroll
            for (int sc = 0; sc < 4; sc++) {
                s16x4 vf = *(const s16x4*)&Vb[d * 64
                    + ((((sc << 1) | (quad >> 1)) ^ (d & 7)) << 3) + ((quad & 1) << 2)];
                Oa[nd] = mfma16(vf, pb[sc], Oa[nd]);
            }
        }
    }

    float r = lsum;
    r += __shfl_xor(r, 16, 64);
    r += __shfl_xor(r, 32, 64);
    const float inv = 1.0f / (r + (float)diagKt * PCONST);
    #pragma unroll
    for (int nd = 0; nd < 4; nd++) {
        u16x4 o;
        #pragma unroll
        for (int i = 0; i < 4; i++) o[i] = f2bf(Oa[nd][i] * inv);
        *(u16x4*)&Ctx[(b * SEQ + q_ln) * DIM + h * DK + nd * 16 + quad * 4] = o;
    }
}

// ---------------- output projection ----------------
__global__ __launch_bounds__(256) void out_gemm(
        const bfraw* __restrict__ Ctx, const bfraw* __restrict__ WoB, float* __restrict__ C) {
    const int m0 = blockIdx.x * 128, n0 = blockIdx.y * 128;
    f32x4 acc[4][4];
    gemm128_core(nullptr, WoB, m0, n0, acc, false, nullptr, Ctx);
    const int lane = threadIdx.x & 63, wave = threadIdx.x >> 6;
    const int lrow = lane & 15, quad = lane >> 4;
    const int wy = wave >> 1, wx = wave & 1;
    #pragma unroll
    for (int mi = 0; mi < 4; mi++)
        #pragma unroll
        for (int ni = 0; ni < 4; ni++)
            #pragma unroll
            for (int i = 0; i < 4; i++) {
                int m = m0 + wy * 64 + mi * 16 + quad * 4 + i;
                int n = n0 + wx * 64 + ni * 16 + lrow;
                C[m * DIM + n] = acc[mi][ni][i];
            }
}

// ---------------- residual + LayerNorm (fp32) ----------------
__global__ __launch_bounds__(256) void ln_kernel(
        const float* __restrict__ C, const float* __restrict__ Xq,
        const float* __restrict__ gamma, const float* __restrict__ beta,
        float* __restrict__ out) {
    __shared__ float rbuf[4];
    const int m = blockIdx.x, tid = threadIdx.x;
    const float* crow = C + m * DIM;
    const float* xrow = Xq + m * DIM;
    float v[4]; float s = 0.f, s2 = 0.f;
    #pragma unroll
    for (int i = 0; i < 4; i++) {
        int d = tid + (i << 8);
        float x = crow[d] + xrow[d];
        v[i] = x; s += x; s2 += x * x;
    }
    float S  = block_reduce(s,  rbuf, 1);
    float S2 = block_reduce(s2, rbuf, 1);
    float mu  = S * (1.0f / DIM);
    float var = S2 * (1.0f / DIM) - mu * mu;
    float rstd = rsqrtf(var + 1e-5f);
    #pragma unroll
    for (int i = 0; i < 4; i++) {
        int d = tid + (i << 8);
        out[m * DIM + d] = (v[i] - mu) * rstd * gamma[d] + beta[d];
    }
}

extern "C" void kernel_launch(void* const* d_in, const int* in_sizes, int n_in,
                              void* d_out, int out_size, void* d_ws, size_t ws_size,
                              hipStream_t stream) {
    const float* Xq    = (const float*)d_in[0];
    const float* Xk    = (const float*)d_in[1];
    const float* Xv    = (const float*)d_in[2];
    const int*   mask  = (const int*)  d_in[3];
    const float* Wq    = (const float*)d_in[4];
    const float* Wk    = (const float*)d_in[5];
    const float* Wv    = (const float*)d_in[6];
    const float* Wo    = (const float*)d_in[7];
    const float* gamma = (const float*)d_in[8];
    const float* beta  = (const float*)d_in[9];
    float* out = (float*)d_out;

    // ws (64 MB): C fp32 [0,16M) | Scum [16,16.25M) | Wb bf16 [24,32M) |
    //             Qp [32,40) Kp [40,48) Vt [48,56) Ctx [56,64)
    char* ws = (char*)d_ws;
    bfraw* Wb   = (bfraw*)(ws + (24u << 20));
    bfraw* Qp   = (bfraw*)(ws + (32u << 20));
    bfraw* Kp   = (bfraw*)(ws + (40u << 20));
    bfraw* Vt   = (bfraw*)(ws + (48u << 20));
    bfraw* Ctx  = (bfraw*)(ws + (56u << 20));
    float* C    = (float*)(ws);
    float* Scum = (float*)(ws + (16u << 20));

    dim3 blk(256);
    cvt_kernel<<<dim3(DIM * DIM / (256 * 8), 4),  blk, 0, stream>>>(Wq, Wk, Wv, Wo, Wb);
    qkv_gemm  <<<dim3(MROWS / 128, DIM / 128, 3), blk, 0, stream>>>(Xq, Xk, Xv, Wb, Qp, Kp, Vt);
    vsum_kernel<<<dim3(BATCH * NH),               blk, 0, stream>>>(Vt, Scum);
    attn_flash<<<dim3(BATCH * NH, SEQ / 64),      blk, 0, stream>>>(Qp, Kp, Vt, Scum, mask, Ctx);
    out_gemm  <<<dim3(MROWS / 128, DIM / 128),    blk, 0, stream>>>(Ctx, Wb + 3 * (DIM * DIM), C);
    ln_kernel <<<dim3(MROWS),                     blk, 0, stream>>>(C, Xq, gamma, beta, out);
}